// Round 3
// baseline (346.549 us; speedup 1.0000x reference)
//
#include <hip/hip_runtime.h>
#include <hip/hip_bf16.h>
#include <cstdint>

// LSTMCell B=8192, IN=H=1024, fp32 in/out.
// R6: faithful m201 8-phase port (4 phases/K-tile, 16 MFMA/phase, double
// barrier, asm lgkmcnt(0) but NO sched_barrier, bF dedup across mh-pair,
// 2 gloads/phase, GATE(8) once per 2 phases). Casts reverted to R4
// (measured non-GEMM 137us there vs 174us with R5 casts).

#define B_DIM 8192
#define H_DIM 1024
#define K2    2048   // IN + H
#define N4    4096   // 4 * H
#define BK    64
#define BM    256
#define BN    256
#define NT    (K2 / BK)   // 32 K-tiles (even; peel assumes it)

typedef __bf16 bf16x8 __attribute__((ext_vector_type(8)));
typedef float  f32x4  __attribute__((ext_vector_type(4)));

__device__ __forceinline__ void async_load16(const __bf16* g, __bf16* l) {
  __builtin_amdgcn_global_load_lds(
      (__attribute__((address_space(1))) void*)(g),
      (__attribute__((address_space(3))) void*)(l),
      16, 0, 0);
}

__device__ __forceinline__ float sigm(float x) {
  return 1.0f / (1.0f + __expf(-x));
}
__device__ __forceinline__ float tanh_fast(float x) {
  return 2.0f / (1.0f + __expf(-2.0f * x)) - 1.0f;
}

// ---------------- cast A = [x | h] -> bf16 [8192][2048] ----------------
__global__ void cast_a(const float* __restrict__ x, const float* __restrict__ h,
                       __bf16* __restrict__ A) {
  int row = blockIdx.x;
  int k = threadIdx.x << 3;  // 0..2040 step 8
  const float* src = (k < H_DIM) ? (x + (size_t)row * H_DIM + k)
                                 : (h + (size_t)row * H_DIM + (k - H_DIM));
  float4 v0 = *(const float4*)src;
  float4 v1 = *(const float4*)(src + 4);
  bf16x8 o;
  o[0] = (__bf16)v0.x; o[1] = (__bf16)v0.y; o[2] = (__bf16)v0.z; o[3] = (__bf16)v0.w;
  o[4] = (__bf16)v1.x; o[5] = (__bf16)v1.y; o[6] = (__bf16)v1.z; o[7] = (__bf16)v1.w;
  *(bf16x8*)&A[(size_t)row * K2 + k] = o;
}

// ------------- cast + transpose + permute weights -> Bt [4096][2048] -------------
// Bt row p = (j>>4)*64 + gate*16 + (j&15); Bt[p][k] = W_cat[k][gate-col j]
// grid: (K2/64, H/32, 4 gates), block 256
__global__ void cast_w(const float* __restrict__ Wii, const float* __restrict__ Wif,
                       const float* __restrict__ Wig, const float* __restrict__ Wio,
                       const float* __restrict__ Whi, const float* __restrict__ Whf,
                       const float* __restrict__ Whg, const float* __restrict__ Who,
                       __bf16* __restrict__ Bt) {
  __shared__ float tile[64][33];
  int k0 = blockIdx.x * 64;
  int j0 = blockIdx.y * 32;
  int gate = blockIdx.z;
  const float* Wi[4] = {Wii, Wif, Wig, Wio};
  const float* Wh[4] = {Whi, Whf, Whg, Who};
  const float* W = (k0 < H_DIM) ? Wi[gate] : Wh[gate];
  int kb = (k0 < H_DIM) ? k0 : (k0 - H_DIM);

  int col = threadIdx.x & 31;
  int rr  = threadIdx.x >> 5;  // 0..7
#pragma unroll
  for (int p = 0; p < 8; ++p)
    tile[p * 8 + rr][col] = W[(size_t)(kb + p * 8 + rr) * H_DIM + j0 + col];
  __syncthreads();

  int jj = threadIdx.x >> 3;   // 0..31
  int ko = threadIdx.x & 7;    // 0..7 (8 k's each)
  int j = j0 + jj;
  int p = ((j >> 4) << 6) + (gate << 4) + (j & 15);
  bf16x8 o;
#pragma unroll
  for (int t = 0; t < 8; ++t) o[t] = (__bf16)tile[ko * 8 + t][jj];
  *(bf16x8*)&Bt[(size_t)p * K2 + k0 + ko * 8] = o;
}

// ---------------- fused GEMM + LSTM gate epilogue (m201 8-phase) ----------------
// grid: 512 blocks (32 M-tiles x 16 N-tiles), block 512 (8 waves, 2M x 4N)
// Phase = { ds_read 4A (+4B if mh0) | 2 global_load_lds | barrier |
//           lgkmcnt(0) | setprio(1) 16 MFMA setprio(0) | [GATE on mh1] | barrier }

#define STAGE_A(D, KH, TT) do { \
    async_load16(gA0 + (size_t)(TT) * 64 + (KH) * 32, &As_s[D][KH][wave << 9]); \
    async_load16(gA1 + (size_t)(TT) * 64 + (KH) * 32, &As_s[D][KH][4096 + (wave << 9)]); \
  } while (0)
#define STAGE_B(D, KH, TT) do { \
    async_load16(gB0 + (size_t)(TT) * 64 + (KH) * 32, &Bs_s[D][KH][wave << 9]); \
    async_load16(gB1 + (size_t)(TT) * 64 + (KH) * 32, &Bs_s[D][KH][4096 + (wave << 9)]); \
  } while (0)

#define DS_A(DB, KK, MH) do { \
    const __bf16* ap_ = &As_s[DB][KK][(wm << 12) + ((MH) << 11) + lane_part]; \
    aF[0] = *(const bf16x8*)(ap_);        aF[1] = *(const bf16x8*)(ap_ + 512); \
    aF[2] = *(const bf16x8*)(ap_ + 1024); aF[3] = *(const bf16x8*)(ap_ + 1536); \
  } while (0)
#define DS_B(DB, KK) do { \
    const __bf16* bp_ = &Bs_s[DB][KK][(wn << 11) + lane_part]; \
    bF[0] = *(const bf16x8*)(bp_);        bF[1] = *(const bf16x8*)(bp_ + 512); \
    bF[2] = *(const bf16x8*)(bp_ + 1024); bF[3] = *(const bf16x8*)(bp_ + 1536); \
  } while (0)

#define MFMA_Q(MH) do { \
    __builtin_amdgcn_s_setprio(1); \
    _Pragma("unroll") \
    for (int i2 = 0; i2 < 4; ++i2) { \
      _Pragma("unroll") \
      for (int n2 = 0; n2 < 4; ++n2) \
        acc[(MH) * 4 + i2][n2] = __builtin_amdgcn_mfma_f32_16x16x32_bf16( \
            aF[i2], bF[n2], acc[(MH) * 4 + i2], 0, 0, 0)[0] == 0.f ? acc[(MH)*4+i2][n2] : acc[(MH)*4+i2][n2]; \
    } \
    __builtin_amdgcn_s_setprio(0); \
  } while (0)
// (placeholder guard removed below -- real MFMA_Q definition)
#undef MFMA_Q
#define MFMA_Q(MH) do { \
    __builtin_amdgcn_s_setprio(1); \
    _Pragma("unroll") \
    for (int i2 = 0; i2 < 4; ++i2) { \
      _Pragma("unroll") \
      for (int n2 = 0; n2 < 4; ++n2) \
        acc[(MH) * 4 + i2][n2] = __builtin_amdgcn_mfma_f32_16x16x32_bf16( \
            aF[i2], bF[n2], acc[(MH) * 4 + i2][n2], 0, 0, 0); \
    } \
    __builtin_amdgcn_s_setprio(0); \
  } while (0)

#define GATE(N) asm volatile("s_waitcnt vmcnt(" #N ")" ::: "memory")
#define BAR()   __builtin_amdgcn_s_barrier()
#define LG0()   asm volatile("s_waitcnt lgkmcnt(0)" ::: "memory")

__global__ __launch_bounds__(512, 2) void lstm_gemm(
    const __bf16* __restrict__ A,    // [8192][2048]
    const __bf16* __restrict__ Bt,   // [4096][2048] permuted rows
    const float* __restrict__ c,
    const float* __restrict__ bi, const float* __restrict__ bf_,
    const float* __restrict__ bg, const float* __restrict__ bo,
    float* __restrict__ out_c, float* __restrict__ out_h) {
  // [buf][khalf][256 rows][32 cols] bf16; row = 64 B = 4 x 16B slots.
  // phys slot s of row r holds global k-segment s ^ ((r>>1)&3).
  __shared__ __align__(16) __bf16 As_s[2][2][256 * 32];   // 64 KB
  __shared__ __align__(16) __bf16 Bs_s[2][2][256 * 32];   // 64 KB

  // bijective XCD swizzle (512 % 8 == 0)
  const int wg  = blockIdx.x;
  const int swz = ((wg & 7) << 6) + (wg >> 3);
  const int bx = swz & 31;          // M tile 0..31
  const int by = swz >> 5;          // N tile 0..15
  const int m0 = bx << 8;
  const int n0 = by << 8;

  const int tid  = threadIdx.x;
  const int wave = tid >> 6;        // 0..7
  const int lane = tid & 63;
  const int wm   = wave >> 2;       // 0..1 : M half (128 rows)
  const int wn   = wave & 3;        // 0..3 : N quarter (64 perm-cols)

  // staging: wave w stages rows w*16+(lane>>2) of each 128-row half; lane
  // writes phys slot lane&3; pre-swizzled source seg = (lane&3)^((lane>>3)&3).
  const int srow = (wave << 4) + (lane >> 2);
  const int sgc  = (lane & 3) ^ ((lane >> 3) & 3);
  const __bf16* gA0 = A  + (size_t)(m0 + srow) * K2 + sgc * 8;
  const __bf16* gA1 = gA0 + (size_t)128 * K2;
  const __bf16* gB0 = Bt + (size_t)(n0 + srow) * K2 + sgc * 8;
  const __bf16* gB1 = gB0 + (size_t)128 * K2;

  // fragment read offset (elems): row=(lane&15), slot=(lane>>4)^((lane>>1)&3)
  const int lane_part = ((lane & 15) << 5) + ((((lane >> 4) ^ ((lane >> 1) & 3))) << 3);

  f32x4 acc[8][4] = {};
  bf16x8 aF[4], bF[4];

  // ---- prologue: A+B(0,0,0), A+B(0,1,0), A+B(1,0,1) = 12 loads/thread ----
  STAGE_A(0, 0, 0); STAGE_B(0, 0, 0);
  STAGE_A(0, 1, 0); STAGE_B(0, 1, 0);
  STAGE_A(1, 0, 1); STAGE_B(1, 0, 1);
  GATE(8);                          // (0,0,0) landed
  BAR();

  // ---- main loop, 2 tiles (8 phases) per iter; static LDS indices ----
  for (int t = 0; t < NT - 2; t += 2) {
    // tile t (buf 0)
    DS_A(0, 0, 0); DS_B(0, 0); STAGE_A(1, 1, t + 1);
    BAR(); LG0(); MFMA_Q(0); BAR();
    DS_A(0, 0, 1);             STAGE_B(1, 1, t + 1);
    BAR(); LG0(); MFMA_Q(1); GATE(8); BAR();
    DS_A(0, 1, 0); DS_B(0, 1); STAGE_A(0, 0, t + 2);
    BAR(); LG0(); MFMA_Q(0); BAR();
    DS_A(0, 1, 1);             STAGE_B(0, 0, t + 2);
    BAR(); LG0(); MFMA_Q(1); GATE(8); BAR();
    // tile t+1 (buf 1)
    DS_A(1, 0, 0); DS_B(1, 0); STAGE_A(0, 1, t + 2);
    BAR(); LG0(); MFMA_Q(0); BAR();
    DS_A(1, 0, 1);             STAGE_B(0, 1, t + 2);
    BAR(); LG0(); MFMA_Q(1); GATE(8); BAR();
    DS_A(1, 1, 0); DS_B(1, 1); STAGE_A(1, 0, t + 3);
    BAR(); LG0(); MFMA_Q(0); BAR();
    DS_A(1, 1, 1);             STAGE_B(1, 0, t + 3);
    BAR(); LG0(); MFMA_Q(1); GATE(8); BAR();
  }

  // ---- peel tile NT-2 (buf 0): stage only (1,1,NT-1) ----
  DS_A(0, 0, 0); DS_B(0, 0); STAGE_A(1, 1, NT - 1);
  BAR(); LG0(); MFMA_Q(0); BAR();
  DS_A(0, 0, 1);             STAGE_B(1, 1, NT - 1);
  BAR(); LG0(); MFMA_Q(1); GATE(8); BAR();
  DS_A(0, 1, 0); DS_B(0, 1);
  BAR(); LG0(); MFMA_Q(0); BAR();
  DS_A(0, 1, 1);
  BAR(); LG0(); MFMA_Q(1); GATE(4); BAR();
  // ---- peel tile NT-1 (buf 1): no staging ----
  DS_A(1, 0, 0); DS_B(1, 0);
  BAR(); LG0(); MFMA_Q(0); BAR();
  DS_A(1, 0, 1);
  BAR(); LG0(); MFMA_Q(1); GATE(0); BAR();
  DS_A(1, 1, 0); DS_B(1, 1);
  BAR(); LG0(); MFMA_Q(0); BAR();
  DS_A(1, 1, 1);
  LG0(); MFMA_Q(1);

  // ---- fused epilogue: gate == n-fragment index, lane-local ----
  // p = n0 + wn*64 + ni*16 + (lane&15)  ->  j = by*64 + wn*16 + (lane&15)
  const int jj = (by << 6) + (wn << 4) + (lane & 15);
  const float vbi = bi[jj], vbf = bf_[jj], vbg = bg[jj], vbo = bo[jj];
  const int row_base = m0 + (wm << 7) + ((lane >> 4) << 2);
#pragma unroll
  for (int mi = 0; mi < 8; ++mi) {
#pragma unroll
    for (int r = 0; r < 4; ++r) {
      const int row = row_base + mi * 16 + r;
      const size_t idx = (size_t)row * H_DIM + jj;
      const float gi = sigm(acc[mi][0][r] + vbi);
      const float gf = sigm(acc[mi][1][r] + vbf);
      const float gg = tanh_fast(acc[mi][2][r] + vbg);
      const float go = sigm(acc[mi][3][r] + vbo);
      const float cv = c[idx];
      const float nc = gf * cv + gi * gg;
      out_c[idx] = nc;
      out_h[idx] = go * tanh_fast(nc);
    }
  }
}

extern "C" void kernel_launch(void* const* d_in, const int* in_sizes, int n_in,
                              void* d_out, int out_size, void* d_ws, size_t ws_size,
                              hipStream_t stream) {
  const float* x   = (const float*)d_in[0];
  const float* c   = (const float*)d_in[1];
  const float* h   = (const float*)d_in[2];
  const float* Wii = (const float*)d_in[3];
  const float* Wif = (const float*)d_in[4];
  const float* Wig = (const float*)d_in[5];
  const float* Wio = (const float*)d_in[6];
  const float* Whi = (const float*)d_in[7];
  const float* Whf = (const float*)d_in[8];
  const float* Whg = (const float*)d_in[9];
  const float* Who = (const float*)d_in[10];
  const float* bi  = (const float*)d_in[11];
  const float* bf_ = (const float*)d_in[12];
  const float* bg  = (const float*)d_in[13];
  const float* bo  = (const float*)d_in[14];

  __bf16* Abf = (__bf16*)d_ws;                                   // 32 MiB
  __bf16* Bt  = (__bf16*)((char*)d_ws + (size_t)B_DIM * K2 * 2); // 16 MiB

  float* out_c = (float*)d_out;
  float* out_h = out_c + (size_t)B_DIM * H_DIM;

  cast_a<<<B_DIM, 256, 0, stream>>>(x, h, Abf);
  dim3 gw(K2 / 64, H_DIM / 32, 4);
  cast_w<<<gw, 256, 0, stream>>>(Wii, Wif, Wig, Wio, Whi, Whf, Whg, Who, Bt);
  lstm_gemm<<<dim3((B_DIM / BM) * (N4 / BN)), 512, 0, stream>>>(
      Abf, Bt, c, bi, bf_, bg, bo, out_c, out_h);
}